// Round 1
// baseline (3314.685 us; speedup 1.0000x reference)
//
#include <hip/hip_runtime.h>
#include <hip/hip_fp16.h>

// Problem constants
#define RF    1024
#define USZ   200
#define MGCC  60
#define FSZ   64
#define NSTG  4
#define NLAY  10
#define NWIN  1600          // N = 8 * 200
#define PXLEN 2624          // N + RF
#define SCALEF 0.70710678118f
#define TPB   512

typedef _Float16 h2t __attribute__((ext_vector_type(2)));
union U4 { uint4 u; h2t h[8]; };

__device__ __forceinline__ float fdot2(h2t a, h2t b, float c) {
#if __has_builtin(__builtin_amdgcn_fdot2)
  return __builtin_amdgcn_fdot2(a, b, c, false);
#else
  return c + (float)a.x * (float)b.x + (float)a.y * (float)b.y;
#endif
}

__device__ __forceinline__ float sigm(float x) { return 1.0f / (1.0f + __expf(-x)); }
__device__ __forceinline__ float tanhfast(float x) { return 1.0f - 2.0f / (__expf(2.0f * x) + 1.0f); }

// -------- prep kernels --------

// cond[n][c] = tanh(mgc[f] . cond_w[u*60+c] + cond_b[u*60+c]),  n = f*200+u
__global__ void k_cond(const float* __restrict__ mgc, const float* __restrict__ cond_w,
                       const float* __restrict__ cond_b, float* __restrict__ cond) {
  int idx = blockIdx.x * 256 + threadIdx.x;   // < 96000
  int n = idx / 60, c = idx % 60;
  int u = n % USZ, f = n / USZ;
  float a = cond_b[u * 60 + c];
  const float* wr = cond_w + (u * 60 + c) * 60;
  const float* mr = mgc + f * 60;
#pragma unroll 10
  for (int m = 0; m < 60; ++m) a += mr[m] * wr[m];
  cond[idx] = tanhfast(a);
}

// icgc[(sl*1600+n)*128 + j*64+o] = cond[n].ccw[sl][j][o] + ccb[sl][j][o] + conv_b[sl][j][o]
__global__ void k_icgc(const float* __restrict__ cond, const float* __restrict__ ccw,
                       const float* __restrict__ ccb, const float* __restrict__ conv_b,
                       float* __restrict__ icgc) {
  int idx = blockIdx.x * 256 + threadIdx.x;   // < 8,192,000
  int o = idx & 63;
  int j = (idx >> 6) & 1;
  int rest = idx >> 7;
  int n = rest % 1600;
  int sl = rest / 1600;                       // s*10+l
  float a = ccb[(sl * 2 + j) * 64 + o] + conv_b[(sl * 3 + j) * 64 + o];
  const float* cw = ccw + ((sl * 2 + j) * 64 + o) * 60;
  const float* cn = cond + n * 60;
#pragma unroll 10
  for (int c = 0; c < 60; ++c) a += cn[c] * cw[c];
  icgc[(sl * 1600 + n) * 128 + j * 64 + o] = a;
}

// f16-pack conv weights: wl[(((c8*3+j)*2+s2)*64+o)*8+cc] = convs_w[s][lp][j][o][c8*8+cc][s2]
__global__ void k_wcvt(const float* __restrict__ convs_w, __half* __restrict__ wlg) {
  int idx = blockIdx.x * 256 + threadIdx.x;   // < 884736
  int w = idx % 24576;
  int sl = idx / 24576;                       // s*9+lp
  int cc = w & 7;
  int o  = (w >> 3) & 63;
  int t  = w >> 9;                            // 0..47
  int s2 = t & 1;
  int jc = t >> 1;                            // 0..23
  int j  = jc % 3;
  int c8 = jc / 3;
  int c  = c8 * 8 + cc;
  float v = convs_w[(((sl * 3 + j) * 64 + o) * 64 + c) * 2 + s2];
  wlg[idx] = __float2half(v);
}

// pwT[s][o][k] = pre_w[s][k][o]
__global__ void k_pwt(const float* __restrict__ pre_w, float* __restrict__ pwT) {
  int idx = blockIdx.x * 256 + threadIdx.x;   // < 65536
  int k = idx & 255, o = (idx >> 8) & 63, s = idx >> 14;
  pwT[idx] = pre_w[(s * 256 + k) * 64 + o];
}

__global__ void k_prefix(const float* __restrict__ noise, float* __restrict__ pxA,
                         float* __restrict__ pxB) {
  int i = blockIdx.x * 256 + threadIdx.x;     // < 1024
  float v = noise[i];
  pxA[i] = v; pxB[i] = v;
}

// -------- main per-window kernel --------
// LDS layout (bytes):
//  wl    @      0  (49152)   staged f16 layer weights
//  actA  @  49152  (65536)   f16 [pos][64]
//  actB  @ 114688  (32768)   f16 [pos][64]
//  xw    @ 147456  ( 4104)   fp32 window samples [1025] (+pad)
//  icg   @ 151560  (  768)   fp32 [192]: inp-add[64], gate-add[64], res-bias[64]
//  x64f  @ 152328  (  256)
//  pre   @ 152584  ( 1024)
//  red   @ 153608  (  128)
#define SMEM_BYTES 153736

__launch_bounds__(TPB, 2)
__global__ void k_window(int s, const float* __restrict__ px, float* __restrict__ ptail,
                         float* __restrict__ out,
                         const float* __restrict__ icgc, const float* __restrict__ conv_b,
                         const float* __restrict__ conv0_w, const __half* __restrict__ wlg,
                         const float* __restrict__ pwT, const float* __restrict__ pre_b,
                         const float* __restrict__ mean_w, const float* __restrict__ mean_b,
                         const float* __restrict__ std_w, const float* __restrict__ std_b) {
  extern __shared__ char smem[];
  __half* wl   = (__half*)smem;
  __half* actA = (__half*)(smem + 49152);
  __half* actB = (__half*)(smem + 114688);
  float*  xw   = (float*)(smem + 147456);
  float*  icg  = (float*)(smem + 151560);
  float*  x64f = (float*)(smem + 152328);
  float*  pre  = (float*)(smem + 152584);
  float*  red  = (float*)(smem + 153608);

  const int n = blockIdx.x;
  const int tid = threadIdx.x;
  const int wave = tid >> 6, lane = tid & 63;   // lane = output channel o

  // load window samples px[n .. n+1024]
  for (int i = tid; i < 1025; i += TPB) xw[i] = px[n + i];
  // layer-0 conditioning adds + res bias
  if (tid < 128) icg[tid] = icgc[((s * 10 + 0) * 1600 + n) * 128 + tid];
  else if (tid < 192) icg[tid] = conv_b[((s * 10 + 0) * 3 + 2) * 64 + (tid - 128)];
  __syncthreads();

  // ---- layer 0 (C=1, K=2) ----
  {
    const int o = lane;
    const float wi0 = conv0_w[((s * 3 + 0) * 64 + o) * 2 + 0];
    const float wi1 = conv0_w[((s * 3 + 0) * 64 + o) * 2 + 1];
    const float wg0 = conv0_w[((s * 3 + 1) * 64 + o) * 2 + 0];
    const float wg1 = conv0_w[((s * 3 + 1) * 64 + o) * 2 + 1];
    const float wr0 = conv0_w[((s * 3 + 2) * 64 + o) * 2 + 0];
    const float wr1 = conv0_w[((s * 3 + 2) * 64 + o) * 2 + 1];
    const float bi = icg[o], bg = icg[64 + o], br = icg[128 + o];
    for (int p = wave; p < 512; p += 8) {
      float x0 = xw[2 * p], x1 = xw[2 * p + 1];
      float vi = bi + x0 * wi0 + x1 * wi1;
      float vg = bg + x0 * wg0 + x1 * wg1;
      float vr = br + x0 * wr0 + x1 * wr1;
      actA[p * 64 + o] = __float2half((tanhfast(vi) * sigm(vg) + vr) * SCALEF);
    }
  }
  __syncthreads();

  // ---- layers 1..9 ----
  for (int l = 1; l <= 9; ++l) {
    const int Lout = 512 >> l;
    // stage conditioning + weights
    if (tid < 128) icg[tid] = icgc[((s * 10 + l) * 1600 + n) * 128 + tid];
    else if (tid < 192) icg[tid] = conv_b[((s * 10 + l) * 3 + 2) * 64 + (tid - 128)];
    const uint4* wsrc = (const uint4*)(wlg + (size_t)(s * 9 + (l - 1)) * 24576);
    uint4* wdst = (uint4*)wl;
    for (int i = tid; i < 3072; i += TPB) wdst[i] = wsrc[i];
    __syncthreads();

    const __half* ain = (l & 1) ? actA : actB;
    __half* aout      = (l & 1) ? actB : actA;
    const int o = lane;
    const int P = (Lout < 8) ? Lout : 8;
    const int ngroups = Lout / P;             // Lout/8, or 1 for tiny layers
    for (int grp = wave; grp < ngroups; grp += 8) {
      const int p0 = grp * P;
      float ai[8], ag[8], ar[8];
#pragma unroll
      for (int pp = 0; pp < 8; ++pp) { ai[pp] = icg[o]; ag[pp] = icg[64 + o]; ar[pp] = icg[128 + o]; }
      for (int c8 = 0; c8 < 8; ++c8) {
        U4 wv[6];
#pragma unroll
        for (int t6 = 0; t6 < 6; ++t6)
          wv[t6].u = *(const uint4*)(wl + ((c8 * 6 + t6) * 64 + o) * 8);
#pragma unroll
        for (int pp = 0; pp < 8; ++pp) {
          const int p = p0 + ((pp < P) ? pp : 0);
          U4 a0, a1;
          a0.u = *(const uint4*)(ain + (2 * p) * 64 + c8 * 8);
          a1.u = *(const uint4*)(ain + (2 * p + 1) * 64 + c8 * 8);
#pragma unroll
          for (int q = 0; q < 4; ++q) {
            ai[pp] = fdot2(a0.h[q], wv[0].h[q], ai[pp]);
            ai[pp] = fdot2(a1.h[q], wv[1].h[q], ai[pp]);
            ag[pp] = fdot2(a0.h[q], wv[2].h[q], ag[pp]);
            ag[pp] = fdot2(a1.h[q], wv[3].h[q], ag[pp]);
            ar[pp] = fdot2(a0.h[q], wv[4].h[q], ar[pp]);
            ar[pp] = fdot2(a1.h[q], wv[5].h[q], ar[pp]);
          }
        }
      }
#pragma unroll
      for (int pp = 0; pp < 8; ++pp) {
        if (pp < P) {
          float ov = (tanhfast(ai[pp]) * sigm(ag[pp]) + ar[pp]) * SCALEF;
          if (l == 9) x64f[o] = ov;
          else aout[(p0 + pp) * 64 + o] = __float2half(ov);
        }
      }
    }
    __syncthreads();
  }

  // ---- head ----
  if (tid < 256) {
    const int k = tid;
    float a = pre_b[s * 256 + k];
#pragma unroll 8
    for (int oo = 0; oo < 64; ++oo)
      a += x64f[oo] * pwT[(s * 64 + oo) * 256 + k];
    pre[k] = fmaxf(a, 0.0f);
  }
  __syncthreads();
  {
    float pm = 0.0f, pv = 0.0f;
    if (tid < 256) {
      float pk = pre[tid];
      pm = pk * mean_w[s * 256 + tid];
      pv = pk * std_w[s * 256 + tid];
    }
    for (int off = 32; off >= 1; off >>= 1) {
      pm += __shfl_down(pm, off, 64);
      pv += __shfl_down(pv, off, 64);
    }
    if (lane == 0) { red[wave] = pm; red[8 + wave] = pv; }
  }
  __syncthreads();
  if (tid == 0) {
    float m = mean_b[s], lv = std_b[s];
#pragma unroll
    for (int w2 = 0; w2 < 8; ++w2) { m += red[w2]; lv += red[8 + w2]; }
    float eps = xw[1024];                       // px[n + RF]
    float nv = eps * __expf(0.5f * lv) + m;
    if (s == 3) { out[n] = nv; out[1600 + n] = m; out[3200 + n] = lv; }
    else ptail[n] = nv;
    if (n >= 576) out[4800 + s * 1024 + (n - 576)] = nv;   // tails: new[-1024:]
  }
}

extern "C" void kernel_launch(void* const* d_in, const int* in_sizes, int n_in,
                              void* d_out, int out_size, void* d_ws, size_t ws_size,
                              hipStream_t stream) {
  (void)in_sizes; (void)n_in; (void)out_size; (void)ws_size;
  const float* mgc     = (const float*)d_in[0];
  const float* noise   = (const float*)d_in[1];
  const float* cond_w  = (const float*)d_in[2];
  const float* cond_b  = (const float*)d_in[3];
  const float* conv0_w = (const float*)d_in[4];
  const float* convs_w = (const float*)d_in[5];
  const float* conv_b  = (const float*)d_in[6];
  const float* ccw     = (const float*)d_in[7];
  const float* ccb     = (const float*)d_in[8];
  const float* pre_w   = (const float*)d_in[9];
  const float* pre_b   = (const float*)d_in[10];
  const float* mean_w  = (const float*)d_in[11];
  const float* mean_b  = (const float*)d_in[12];
  const float* std_w   = (const float*)d_in[13];
  const float* std_b   = (const float*)d_in[14];
  float* out = (float*)d_out;

  float* ws_f = (float*)d_ws;
  float*  cond = ws_f;                    // 96000 f
  float*  icgc = cond + 96000;            // 8,192,000 f
  float*  pxA  = icgc + 8192000;          // 2624 f
  float*  pxB  = pxA + 2624;              // 2624 f
  float*  pwT  = pxB + 2624;              // 65536 f
  __half* wlg  = (__half*)(pwT + 65536);  // 884736 halfs (offset is 16B-aligned)

  k_cond<<<375, 256, 0, stream>>>(mgc, cond_w, cond_b, cond);
  k_icgc<<<32000, 256, 0, stream>>>(cond, ccw, ccb, conv_b, icgc);
  k_wcvt<<<3456, 256, 0, stream>>>(convs_w, wlg);
  k_pwt<<<256, 256, 0, stream>>>(pre_w, pwT);
  k_prefix<<<4, 256, 0, stream>>>(noise, pxA, pxB);

  (void)hipFuncSetAttribute((const void*)k_window,
                            hipFuncAttributeMaxDynamicSharedMemorySize, SMEM_BYTES);

  for (int s = 0; s < 4; ++s) {
    const float* pin = (s == 0) ? noise : (s == 1 ? pxA : (s == 2 ? pxB : pxA));
    float* pt = (s == 0) ? (pxA + 1024) : (s == 1 ? (pxB + 1024) : (s == 2 ? (pxA + 1024) : nullptr));
    k_window<<<NWIN, TPB, SMEM_BYTES, stream>>>(s, pin, pt, out, icgc, conv_b, conv0_w,
                                                wlg, pwT, pre_b, mean_w, mean_b, std_w, std_b);
  }
}

// Round 2
// 1243.114 us; speedup vs baseline: 2.6664x; 2.6664x over previous
//
#include <hip/hip_runtime.h>
#include <hip/hip_fp16.h>

// Problem constants
#define RF    1024
#define USZ   200
#define NWIN  1600          // N = 8 * 200
#define SCALEF 0.70710678118f
#define TPB   512
#define CSTR  72            // act channel stride in halfs: 144 B rows (16B-aligned, 4-bank skew)

typedef _Float16 f16x8 __attribute__((ext_vector_type(8)));
typedef float    f32x4 __attribute__((ext_vector_type(4)));

__device__ __forceinline__ float sigm(float x) { return 1.0f / (1.0f + __expf(-x)); }
__device__ __forceinline__ float tanhfast(float x) { return 1.0f - 2.0f / (__expf(2.0f * x) + 1.0f); }

// -------- prep kernels --------

// cond[n][c] = tanh(mgc[f] . cond_w[u*60+c] + cond_b[u*60+c]),  n = f*200+u
__global__ void k_cond(const float* __restrict__ mgc, const float* __restrict__ cond_w,
                       const float* __restrict__ cond_b, float* __restrict__ cond) {
  int idx = blockIdx.x * 256 + threadIdx.x;   // < 96000
  int n = idx / 60, c = idx % 60;
  int u = n % USZ, f = n / USZ;
  float a = cond_b[u * 60 + c];
  const float* wr = cond_w + (u * 60 + c) * 60;
  const float* mr = mgc + f * 60;
#pragma unroll 10
  for (int m = 0; m < 60; ++m) a += mr[m] * wr[m];
  cond[idx] = tanhfast(a);
}

// icgc[(sl*1600+n)*128 + j*64+o] = cond[n].ccw[sl][j][o] + ccb[sl][j][o] + conv_b[sl][j][o]
__global__ void k_icgc(const float* __restrict__ cond, const float* __restrict__ ccw,
                       const float* __restrict__ ccb, const float* __restrict__ conv_b,
                       float* __restrict__ icgc) {
  int idx = blockIdx.x * 256 + threadIdx.x;   // < 8,192,000
  int o = idx & 63;
  int j = (idx >> 6) & 1;
  int rest = idx >> 7;
  int n = rest % 1600;
  int sl = rest / 1600;                       // s*10+l
  float a = ccb[(sl * 2 + j) * 64 + o] + conv_b[(sl * 3 + j) * 64 + o];
  const float* cw = ccw + ((sl * 2 + j) * 64 + o) * 60;
  const float* cn = cond + n * 60;
#pragma unroll 10
  for (int c = 0; c < 60; ++c) a += cn[c] * cw[c];
  icgc[(sl * 1600 + n) * 128 + j * 64 + o] = a;
}

// B-fragment pack for mfma_f32_16x16x32_f16:
// wfrag[((((sl*3+gate)*4+ch16)*4+ks)*64+lane)*8+j] = W[k][n] with
//   n = ch16*16 + (lane&15), k = ks*32 + (lane>>4)*8 + j, k = s2*64 + c
__global__ void k_wcvt(const float* __restrict__ convs_w, _Float16* __restrict__ wfrag) {
  int idx = blockIdx.x * 256 + threadIdx.x;   // < 884736
  int j    = idx & 7;
  int lane = (idx >> 3) & 63;
  int ks   = (idx >> 9) & 3;
  int ch16 = (idx >> 11) & 3;
  int t    = idx >> 13;                       // sl*3 + gate
  int gate = t % 3, sl = t / 3;               // sl = s*9 + (l-1)
  int o  = ch16 * 16 + (lane & 15);
  int kk = ks * 32 + (lane >> 4) * 8 + j;
  int s2 = kk >> 6, c = kk & 63;
  wfrag[idx] = (_Float16)convs_w[(((sl * 3 + gate) * 64 + o) * 64 + c) * 2 + s2];
}

// pwT[s][o][k] = pre_w[s][k][o]
__global__ void k_pwt(const float* __restrict__ pre_w, float* __restrict__ pwT) {
  int idx = blockIdx.x * 256 + threadIdx.x;   // < 65536
  int k = idx & 255, o = (idx >> 8) & 63, s = idx >> 14;
  pwT[idx] = pre_w[(s * 256 + k) * 64 + o];
}

__global__ void k_prefix(const float* __restrict__ noise, float* __restrict__ pxA,
                         float* __restrict__ pxB) {
  int i = blockIdx.x * 256 + threadIdx.x;     // < 1024
  float v = noise[i];
  pxA[i] = v; pxB[i] = v;
}

// -------- main per-window kernel (MFMA) --------
// LDS layout (bytes):
//  actA @      0  (73728)  f16 [512 pos][CSTR]
//  actB @  73728  (36864)  f16 [256 pos][CSTR]
//  xw   @ 110592  ( 4112)  fp32 window samples [1025]
//  x64f @ 114704  (  256)
//  pre  @ 114960  ( 1024)
//  red  @ 115984  (   64)
#define SMEM_BYTES 116048

__launch_bounds__(TPB, 2)
__global__ void k_window(int s, const float* __restrict__ px, float* __restrict__ ptail,
                         float* __restrict__ out,
                         const float* __restrict__ icgc, const float* __restrict__ conv_b,
                         const float* __restrict__ conv0_w, const _Float16* __restrict__ wfrag,
                         const float* __restrict__ pwT, const float* __restrict__ pre_b,
                         const float* __restrict__ mean_w, const float* __restrict__ mean_b,
                         const float* __restrict__ std_w, const float* __restrict__ std_b) {
  extern __shared__ char smem[];
  _Float16* actA = (_Float16*)smem;
  _Float16* actB = (_Float16*)(smem + 73728);
  float*    xw   = (float*)(smem + 110592);
  float*    x64f = (float*)(smem + 114704);
  float*    pre  = (float*)(smem + 114960);
  float*    red  = (float*)(smem + 115984);

  const int n = blockIdx.x;
  const int tid = threadIdx.x;
  const int wave = tid >> 6, lane = tid & 63;
  const int q = lane >> 4, m16 = lane & 15;
  const int ch16 = wave & 3, mstart = wave >> 2;   // wave -> N-group + M-tile offset
  const int och = ch16 * 16 + m16;                 // output channel in MFMA epilogue

  // stage window samples
  for (int i = tid; i < 1025; i += TPB) xw[i] = px[n + i];
  __syncthreads();

  // ---- layer 0 (C=1, K=2): VALU, lane = channel ----
  {
    const int o = lane;
    const int b0 = ((s * 10 + 0) * 1600 + n) * 128;
    const float bi = icgc[b0 + o];
    const float bg = icgc[b0 + 64 + o];
    const float br = conv_b[((s * 10 + 0) * 3 + 2) * 64 + o];
    const float wi0 = conv0_w[((s * 3 + 0) * 64 + o) * 2 + 0];
    const float wi1 = conv0_w[((s * 3 + 0) * 64 + o) * 2 + 1];
    const float wg0 = conv0_w[((s * 3 + 1) * 64 + o) * 2 + 0];
    const float wg1 = conv0_w[((s * 3 + 1) * 64 + o) * 2 + 1];
    const float wr0 = conv0_w[((s * 3 + 2) * 64 + o) * 2 + 0];
    const float wr1 = conv0_w[((s * 3 + 2) * 64 + o) * 2 + 1];
    for (int p = wave; p < 512; p += 8) {
      float x0 = xw[2 * p], x1 = xw[2 * p + 1];
      float vi = bi + x0 * wi0 + x1 * wi1;
      float vg = bg + x0 * wg0 + x1 * wg1;
      float vr = br + x0 * wr0 + x1 * wr1;
      actA[p * CSTR + o] = (_Float16)((tanhfast(vi) * sigm(vg) + vr) * SCALEF);
    }
  }
  __syncthreads();

  // ---- layers 1..9: MFMA 16x16x32 f16 ----
  for (int l = 1; l <= 9; ++l) {
    const int Lout = 512 >> l;
    const int mtiles = (Lout + 15) >> 4;
    const _Float16* ain = (l & 1) ? actA : actB;
    _Float16* aout      = (l & 1) ? actB : actA;

    if (mstart < mtiles) {
      // per-wave B fragments streamed from global (L2-resident, fragment-packed)
      const f16x8* wb = (const f16x8*)(wfrag + (size_t)(s * 9 + (l - 1)) * 24576);
      f16x8 bfr[3][4];
#pragma unroll
      for (int g = 0; g < 3; ++g)
#pragma unroll
        for (int ks = 0; ks < 4; ++ks)
          bfr[g][ks] = wb[(((g * 4 + ch16) * 4 + ks) << 6) + lane];

      const int base = ((s * 10 + l) * 1600 + n) * 128;
      const float bi = icgc[base + och];
      const float bg = icgc[base + 64 + och];
      const float br = conv_b[((s * 10 + l) * 3 + 2) * 64 + och];

      for (int mt = mstart; mt < mtiles; mt += 2) {
        f32x4 ai = {bi, bi, bi, bi};
        f32x4 ag = {bg, bg, bg, bg};
        f32x4 ar = {br, br, br, br};
#pragma unroll
        for (int ks = 0; ks < 4; ++ks) {
          // A[m][k]: m = m16 (pos within tile), k = q*8.. ; k = s2*64 + c
          const int row = 2 * (mt * 16 + m16) + (ks >> 1);
          const f16x8 af = *(const f16x8*)(ain + row * CSTR + (ks & 1) * 32 + q * 8);
          ai = __builtin_amdgcn_mfma_f32_16x16x32_f16(af, bfr[0][ks], ai, 0, 0, 0);
          ag = __builtin_amdgcn_mfma_f32_16x16x32_f16(af, bfr[1][ks], ag, 0, 0, 0);
          ar = __builtin_amdgcn_mfma_f32_16x16x32_f16(af, bfr[2][ks], ar, 0, 0, 0);
        }
        // epilogue: D[row][col]: col = m16 (channel), row = q*4 + r (position)
#pragma unroll
        for (int r = 0; r < 4; ++r) {
          const int p = mt * 16 + q * 4 + r;
          const float val = (tanhfast(ai[r]) * sigm(ag[r]) + ar[r]) * SCALEF;
          if (l == 9) {
            if (p == 0) x64f[och] = val;
          } else if (p < Lout) {
            aout[p * CSTR + och] = (_Float16)val;
          }
        }
      }
    }
    __syncthreads();
  }

  // ---- head ----
  if (tid < 256) {
    const int k = tid;
    float a = pre_b[s * 256 + k];
#pragma unroll 8
    for (int oo = 0; oo < 64; ++oo)
      a += x64f[oo] * pwT[(s * 64 + oo) * 256 + k];
    pre[k] = fmaxf(a, 0.0f);
  }
  __syncthreads();
  {
    float pm = 0.0f, pv = 0.0f;
    if (tid < 256) {
      float pk = pre[tid];
      pm = pk * mean_w[s * 256 + tid];
      pv = pk * std_w[s * 256 + tid];
    }
    for (int off = 32; off >= 1; off >>= 1) {
      pm += __shfl_down(pm, off, 64);
      pv += __shfl_down(pv, off, 64);
    }
    if (lane == 0) { red[wave] = pm; red[8 + wave] = pv; }
  }
  __syncthreads();
  if (tid == 0) {
    float m = mean_b[s], lv = std_b[s];
#pragma unroll
    for (int w2 = 0; w2 < 8; ++w2) { m += red[w2]; lv += red[8 + w2]; }
    float eps = xw[1024];                       // px[n + RF]
    float nv = eps * __expf(0.5f * lv) + m;
    if (s == 3) { out[n] = nv; out[1600 + n] = m; out[3200 + n] = lv; }
    else ptail[n] = nv;
    if (n >= 576) out[4800 + s * 1024 + (n - 576)] = nv;   // tails: new[-1024:]
  }
}

extern "C" void kernel_launch(void* const* d_in, const int* in_sizes, int n_in,
                              void* d_out, int out_size, void* d_ws, size_t ws_size,
                              hipStream_t stream) {
  (void)in_sizes; (void)n_in; (void)out_size; (void)ws_size;
  const float* mgc     = (const float*)d_in[0];
  const float* noise   = (const float*)d_in[1];
  const float* cond_w  = (const float*)d_in[2];
  const float* cond_b  = (const float*)d_in[3];
  const float* conv0_w = (const float*)d_in[4];
  const float* convs_w = (const float*)d_in[5];
  const float* conv_b  = (const float*)d_in[6];
  const float* ccw     = (const float*)d_in[7];
  const float* ccb     = (const float*)d_in[8];
  const float* pre_w   = (const float*)d_in[9];
  const float* pre_b   = (const float*)d_in[10];
  const float* mean_w  = (const float*)d_in[11];
  const float* mean_b  = (const float*)d_in[12];
  const float* std_w   = (const float*)d_in[13];
  const float* std_b   = (const float*)d_in[14];
  float* out = (float*)d_out;

  float* ws_f = (float*)d_ws;
  float*    cond  = ws_f;                      // 96000 f
  float*    icgc  = cond + 96000;              // 8,192,000 f
  float*    pxA   = icgc + 8192000;            // 2624 f
  float*    pxB   = pxA + 2624;                // 2624 f
  float*    pwT   = pxB + 2624;                // 65536 f
  _Float16* wfrag = (_Float16*)(pwT + 65536);  // 884736 halfs

  k_cond<<<375, 256, 0, stream>>>(mgc, cond_w, cond_b, cond);
  k_icgc<<<32000, 256, 0, stream>>>(cond, ccw, ccb, conv_b, icgc);
  k_wcvt<<<3456, 256, 0, stream>>>(convs_w, wfrag);
  k_pwt<<<256, 256, 0, stream>>>(pre_w, pwT);
  k_prefix<<<4, 256, 0, stream>>>(noise, pxA, pxB);

  (void)hipFuncSetAttribute((const void*)k_window,
                            hipFuncAttributeMaxDynamicSharedMemorySize, SMEM_BYTES);

  for (int s = 0; s < 4; ++s) {
    const float* pin = (s == 0) ? noise : (s == 1 ? pxA : (s == 2 ? pxB : pxA));
    float* pt = (s == 0) ? (pxA + 1024) : (s == 1 ? (pxB + 1024) : (s == 2 ? (pxA + 1024) : nullptr));
    k_window<<<NWIN, TPB, SMEM_BYTES, stream>>>(s, pin, pt, out, icgc, conv_b, conv0_w,
                                                wfrag, pwT, pre_b, mean_w, mean_b, std_w, std_b);
  }
}

// Round 3
// 664.475 us; speedup vs baseline: 4.9884x; 1.8708x over previous
//
#include <hip/hip_runtime.h>
#include <hip/hip_fp16.h>

// Problem constants
#define RF    1024
#define USZ   200
#define NWIN  1600          // N = 8 * 200
#define SCALEF 0.70710678118f
#define TPB   512
#define CSTR  72            // act channel stride in halfs: 144 B rows (16B-aligned, 4-bank skew)

typedef _Float16 f16x8 __attribute__((ext_vector_type(8)));
typedef float    f32x4 __attribute__((ext_vector_type(4)));

#if __has_builtin(__builtin_amdgcn_exp2f)
#define EXP2F(x) __builtin_amdgcn_exp2f(x)
#else
#define EXP2F(x) exp2f(x)
#endif
#if __has_builtin(__builtin_amdgcn_rcpf)
#define RCPF(x) __builtin_amdgcn_rcpf(x)
#else
#define RCPF(x) (1.0f / (x))
#endif

// (tanh(a)*sigmoid(g) + r) * SCALEF with 2 exp + 1 rcp:
// tanh(a) = (u-1)/(u+1), u=e^{2a}; sigm(g) = v/(v+1), v=e^{g}
__device__ __forceinline__ float gatecomb(float a, float g, float r) {
  a = fminf(a, 12.0f);          // overflow guard (never active for real data)
  g = fminf(g, 12.0f);
  const float u = EXP2F(a * 2.885390082f);   // e^{2a}
  const float v = EXP2F(g * 1.442695041f);   // e^{g}
  const float d = RCPF((u + 1.0f) * (v + 1.0f));
  return fmaf((u - 1.0f) * v, d, r) * SCALEF;
}

// -------- prep kernels --------

// cond[n][c] = tanh(mgc[f] . cond_w[u*60+c] + cond_b[u*60+c]),  n = f*200+u
__global__ void k_cond(const float* __restrict__ mgc, const float* __restrict__ cond_w,
                       const float* __restrict__ cond_b, float* __restrict__ cond) {
  int idx = blockIdx.x * 256 + threadIdx.x;   // < 96000
  int n = idx / 60, c = idx % 60;
  int u = n % USZ, f = n / USZ;
  float a = cond_b[u * 60 + c];
  const float* wr = cond_w + (u * 60 + c) * 60;
  const float* mr = mgc + f * 60;
#pragma unroll 10
  for (int m = 0; m < 60; ++m) a = fmaf(mr[m], wr[m], a);
  // exact-enough tanh for conditioning
  float e = EXP2F(a * 2.885390082f);
  cond[idx] = (e - 1.0f) * RCPF(e + 1.0f);
}

// icgc[(sl*1600+n)*128 + j*64+o] = cond[n].ccw[sl][j][o] + ccb[sl][j][o] + conv_b[sl][j][o]
// block = (ntile of 32 windows, sl); weights in registers, cond tile in LDS.
__global__ void k_icgc2(const float* __restrict__ cond, const float* __restrict__ ccw,
                        const float* __restrict__ ccb, const float* __restrict__ conv_b,
                        float* __restrict__ icgc) {
  __shared__ float lc[32 * 60];
  const int sl = blockIdx.y;                  // s*10 + l, < 40... actually < 80 (s*10+l spans 40; here sl indexes s*10+l 0..39? see launch)
  const int n0 = blockIdx.x * 32;
  const int tid = threadIdx.x;
  for (int i = tid; i < 1920; i += 256) lc[i] = cond[n0 * 60 + i];
  __syncthreads();
  const int jo = tid & 127;                   // j*64 + o
  const int nh = tid >> 7;                    // 0/1
  const int j = jo >> 6, o = jo & 63;
  float w[60];
  const float* cw = ccw + ((sl * 2 + j) * 64 + o) * 60;
#pragma unroll
  for (int c = 0; c < 60; ++c) w[c] = cw[c];
  const float b = ccb[(sl * 2 + j) * 64 + o] + conv_b[(sl * 3 + j) * 64 + o];
  for (int nl = nh * 16; nl < nh * 16 + 16; ++nl) {
    float a = b;
    const float4* lc4 = (const float4*)(lc + nl * 60);
#pragma unroll
    for (int c4 = 0; c4 < 15; ++c4) {
      const float4 cv = lc4[c4];
      a = fmaf(cv.x, w[c4 * 4 + 0], a);
      a = fmaf(cv.y, w[c4 * 4 + 1], a);
      a = fmaf(cv.z, w[c4 * 4 + 2], a);
      a = fmaf(cv.w, w[c4 * 4 + 3], a);
    }
    icgc[((size_t)sl * 1600 + n0 + nl) * 128 + jo] = a;
  }
}

// B-fragment pack for mfma_f32_16x16x32_f16:
// wfrag[((((sl*3+gate)*4+ch16)*4+ks)*64+lane)*8+j] = W[k][n] with
//   n = ch16*16 + (lane&15), k = ks*32 + (lane>>4)*8 + j, k = s2*64 + c
__global__ void k_wcvt(const float* __restrict__ convs_w, _Float16* __restrict__ wfrag) {
  int idx = blockIdx.x * 256 + threadIdx.x;   // < 884736
  int j    = idx & 7;
  int lane = (idx >> 3) & 63;
  int ks   = (idx >> 9) & 3;
  int ch16 = (idx >> 11) & 3;
  int t    = idx >> 13;                       // sl*3 + gate
  int gate = t % 3, sl = t / 3;               // sl = s*9 + (l-1)
  int o  = ch16 * 16 + (lane & 15);
  int kk = ks * 32 + (lane >> 4) * 8 + j;
  int s2 = kk >> 6, c = kk & 63;
  wfrag[idx] = (_Float16)convs_w[(((sl * 3 + gate) * 64 + o) * 64 + c) * 2 + s2];
}

// pwT[s][o][k] = pre_w[s][k][o]
__global__ void k_pwt(const float* __restrict__ pre_w, float* __restrict__ pwT) {
  int idx = blockIdx.x * 256 + threadIdx.x;   // < 65536
  int k = idx & 255, o = (idx >> 8) & 63, s = idx >> 14;
  pwT[idx] = pre_w[(s * 256 + k) * 64 + o];
}

__global__ void k_prefix(const float* __restrict__ noise, float* __restrict__ pxA,
                         float* __restrict__ pxB) {
  int i = blockIdx.x * 256 + threadIdx.x;     // < 1024
  float v = noise[i];
  pxA[i] = v; pxB[i] = v;
}

// -------- main per-window kernel (MFMA, 2 blocks/CU) --------
// LDS layout (bytes):
//  bufA @      0  (36864)  f16 [256 rows][CSTR]
//  bufB @  36864  (36864)  f16 [256 rows][CSTR]
//  xw   @  73728  ( 4112)  fp32 window samples [1025]
//  x64f @  77840  (  256)
//  pre  @  78096  ( 1024)
//  red  @  79120  (   64)
#define SMEM_BYTES 79184

__device__ __forceinline__ void run_mfma_tiles(
    const _Float16* __restrict__ ain, _Float16* __restrict__ aout, float* __restrict__ x64f,
    const f16x8 bfr[3][4], float bi, float bg, float br,
    int mt_lo, int mt_hi, int row_sub, int Lout, bool last,
    int q, int m16, int och)
{
  for (int mt = mt_lo; mt < mt_hi; mt += 2) {
    f32x4 ai = {bi, bi, bi, bi};
    f32x4 ag = {bg, bg, bg, bg};
    f32x4 ar = {br, br, br, br};
#pragma unroll
    for (int ks = 0; ks < 4; ++ks) {
      // A[m][k]: m = m16 (pos within tile), k = ks*32 + q*8 + j; k = s2*64 + c
      const int row = 2 * (mt * 16 + m16) + (ks >> 1) - row_sub;
      const f16x8 af = *(const f16x8*)(ain + row * CSTR + (ks & 1) * 32 + q * 8);
      ai = __builtin_amdgcn_mfma_f32_16x16x32_f16(af, bfr[0][ks], ai, 0, 0, 0);
      ag = __builtin_amdgcn_mfma_f32_16x16x32_f16(af, bfr[1][ks], ag, 0, 0, 0);
      ar = __builtin_amdgcn_mfma_f32_16x16x32_f16(af, bfr[2][ks], ar, 0, 0, 0);
    }
    // epilogue: D[row][col]: col = m16 (channel), row = q*4 + r (position)
#pragma unroll
    for (int r = 0; r < 4; ++r) {
      const int p = mt * 16 + q * 4 + r;
      const float val = gatecomb(ai[r], ag[r], ar[r]);
      if (last) { if (p == 0) x64f[och] = val; }
      else if (p < Lout) aout[p * CSTR + och] = (_Float16)val;
    }
  }
}

__launch_bounds__(TPB, 4)
__global__ void k_window(int s, const float* __restrict__ px, float* __restrict__ ptail,
                         float* __restrict__ out,
                         const float* __restrict__ icgc, const float* __restrict__ conv_b,
                         const float* __restrict__ conv0_w, const _Float16* __restrict__ wfrag,
                         const float* __restrict__ pwT, const float* __restrict__ pre_b,
                         const float* __restrict__ mean_w, const float* __restrict__ mean_b,
                         const float* __restrict__ std_w, const float* __restrict__ std_b) {
  extern __shared__ char smem[];
  _Float16* bufA = (_Float16*)smem;
  _Float16* bufB = (_Float16*)(smem + 36864);
  float*    xw   = (float*)(smem + 73728);
  float*    x64f = (float*)(smem + 77840);
  float*    pre  = (float*)(smem + 78096);
  float*    red  = (float*)(smem + 79120);

  const int n = blockIdx.x;
  const int tid = threadIdx.x;
  const int wave = tid >> 6, lane = tid & 63;
  const int q = lane >> 4, m16 = lane & 15;
  const int ch16 = wave & 3, mstart = wave >> 2;   // wave -> N-group + M-tile offset
  const int och = ch16 * 16 + m16;

  // stage window samples
  for (int i = tid; i < 1025; i += TPB) xw[i] = px[n + i];

  // layer-0 per-lane constants (lane = channel)
  const int b0 = ((s * 10 + 0) * 1600 + n) * 128;
  const float l0bi = icgc[b0 + lane];
  const float l0bg = icgc[b0 + 64 + lane];
  const float l0br = conv_b[((s * 10 + 0) * 3 + 2) * 64 + lane];
  const float wi0 = conv0_w[((s * 3 + 0) * 64 + lane) * 2 + 0];
  const float wi1 = conv0_w[((s * 3 + 0) * 64 + lane) * 2 + 1];
  const float wg0 = conv0_w[((s * 3 + 1) * 64 + lane) * 2 + 0];
  const float wg1 = conv0_w[((s * 3 + 1) * 64 + lane) * 2 + 1];
  const float wr0 = conv0_w[((s * 3 + 2) * 64 + lane) * 2 + 0];
  const float wr1 = conv0_w[((s * 3 + 2) * 64 + lane) * 2 + 1];

  // layer-1 B fragments + biases (held across the chunked phase)
  f16x8 bfr1[3][4];
  {
    const f16x8* wb = (const f16x8*)(wfrag + (size_t)(s * 9) * 24576);
#pragma unroll
    for (int g = 0; g < 3; ++g)
#pragma unroll
      for (int ks = 0; ks < 4; ++ks)
        bfr1[g][ks] = wb[(((g * 4 + ch16) * 4 + ks) << 6) + lane];
  }
  const int base1 = ((s * 10 + 1) * 1600 + n) * 128;
  const float bi1 = icgc[base1 + och];
  const float bg1 = icgc[base1 + 64 + och];
  const float br1 = conv_b[((s * 10 + 1) * 3 + 2) * 64 + och];

  __syncthreads();

  // ---- layer 0 chunk 0: global pos 0..255 -> bufA ----
#pragma unroll 1
  for (int p = wave; p < 256; p += 8) {
    const float x0 = xw[2 * p], x1 = xw[2 * p + 1];
    const float vi = fmaf(x1, wi1, fmaf(x0, wi0, l0bi));
    const float vg = fmaf(x1, wg1, fmaf(x0, wg0, l0bg));
    const float vr = fmaf(x1, wr1, fmaf(x0, wr0, l0br));
    bufA[p * CSTR + lane] = (_Float16)gatecomb(vi, vg, vr);
  }
  __syncthreads();

  // ---- layer 1 chunk A: out-pos 0..127 (tiles 0..7) <- bufA rows 0..255 ----
  run_mfma_tiles(bufA, bufB, x64f, bfr1, bi1, bg1, br1, mstart, 8, 0, 256, false, q, m16, och);
  __syncthreads();

  // ---- layer 0 chunk 1: global pos 256..511 -> bufA rows 0..255 ----
#pragma unroll 1
  for (int p = wave; p < 256; p += 8) {
    const int pg = 256 + p;
    const float x0 = xw[2 * pg], x1 = xw[2 * pg + 1];
    const float vi = fmaf(x1, wi1, fmaf(x0, wi0, l0bi));
    const float vg = fmaf(x1, wg1, fmaf(x0, wg0, l0bg));
    const float vr = fmaf(x1, wr1, fmaf(x0, wr0, l0br));
    bufA[p * CSTR + lane] = (_Float16)gatecomb(vi, vg, vr);
  }
  __syncthreads();

  // ---- layer 1 chunk B: out-pos 128..255 (tiles 8..15), rows offset by -256 ----
  run_mfma_tiles(bufA, bufB, x64f, bfr1, bi1, bg1, br1, 8 + mstart, 16, 256, 256, false, q, m16, och);
  __syncthreads();

  // ---- layers 2..9: ping-pong bufB/bufA ----
  for (int l = 2; l <= 9; ++l) {
    const int Lout = 512 >> l;
    const int mtiles = (Lout + 15) >> 4;
    const _Float16* ain = (l & 1) ? bufA : bufB;
    _Float16* aout      = (l & 1) ? bufB : bufA;
    f16x8 bfr[3][4];
    const f16x8* wb = (const f16x8*)(wfrag + (size_t)(s * 9 + (l - 1)) * 24576);
#pragma unroll
    for (int g = 0; g < 3; ++g)
#pragma unroll
      for (int ks = 0; ks < 4; ++ks)
        bfr[g][ks] = wb[(((g * 4 + ch16) * 4 + ks) << 6) + lane];
    const int base = ((s * 10 + l) * 1600 + n) * 128;
    run_mfma_tiles(ain, aout, x64f, bfr,
                   icgc[base + och], icgc[base + 64 + och],
                   conv_b[((s * 10 + l) * 3 + 2) * 64 + och],
                   mstart, mtiles, 0, Lout, l == 9, q, m16, och);
    __syncthreads();
  }

  // ---- head ----
  if (tid < 256) {
    const int k = tid;
    float a = pre_b[s * 256 + k];
#pragma unroll 8
    for (int oo = 0; oo < 64; ++oo)
      a = fmaf(x64f[oo], pwT[(s * 64 + oo) * 256 + k], a);
    pre[k] = fmaxf(a, 0.0f);
  }
  __syncthreads();
  {
    float pm = 0.0f, pv = 0.0f;
    if (tid < 256) {
      float pk = pre[tid];
      pm = pk * mean_w[s * 256 + tid];
      pv = pk * std_w[s * 256 + tid];
    }
    for (int off = 32; off >= 1; off >>= 1) {
      pm += __shfl_down(pm, off, 64);
      pv += __shfl_down(pv, off, 64);
    }
    if (lane == 0) { red[wave] = pm; red[8 + wave] = pv; }
  }
  __syncthreads();
  if (tid == 0) {
    float m = mean_b[s], lv = std_b[s];
#pragma unroll
    for (int w2 = 0; w2 < 8; ++w2) { m += red[w2]; lv += red[8 + w2]; }
    float eps = xw[1024];                       // px[n + RF]
    float nv = eps * __expf(0.5f * lv) + m;
    if (s == 3) { out[n] = nv; out[1600 + n] = m; out[3200 + n] = lv; }
    else ptail[n] = nv;
    if (n >= 576) out[4800 + s * 1024 + (n - 576)] = nv;   // tails: new[-1024:]
  }
}

extern "C" void kernel_launch(void* const* d_in, const int* in_sizes, int n_in,
                              void* d_out, int out_size, void* d_ws, size_t ws_size,
                              hipStream_t stream) {
  (void)in_sizes; (void)n_in; (void)out_size; (void)ws_size;
  const float* mgc     = (const float*)d_in[0];
  const float* noise   = (const float*)d_in[1];
  const float* cond_w  = (const float*)d_in[2];
  const float* cond_b  = (const float*)d_in[3];
  const float* conv0_w = (const float*)d_in[4];
  const float* convs_w = (const float*)d_in[5];
  const float* conv_b  = (const float*)d_in[6];
  const float* ccw     = (const float*)d_in[7];
  const float* ccb     = (const float*)d_in[8];
  const float* pre_w   = (const float*)d_in[9];
  const float* pre_b   = (const float*)d_in[10];
  const float* mean_w  = (const float*)d_in[11];
  const float* mean_b  = (const float*)d_in[12];
  const float* std_w   = (const float*)d_in[13];
  const float* std_b   = (const float*)d_in[14];
  float* out = (float*)d_out;

  float* ws_f = (float*)d_ws;
  float*    cond  = ws_f;                      // 96000 f
  float*    icgc  = cond + 96000;              // 8,192,000 f
  float*    pxA   = icgc + 8192000;            // 2624 f
  float*    pxB   = pxA + 2624;                // 2624 f
  float*    pwT   = pxB + 2624;                // 65536 f
  _Float16* wfrag = (_Float16*)(pwT + 65536);  // 884736 halfs

  k_cond<<<375, 256, 0, stream>>>(mgc, cond_w, cond_b, cond);
  k_icgc2<<<dim3(50, 40), 256, 0, stream>>>(cond, ccw, ccb, conv_b, icgc);
  k_wcvt<<<3456, 256, 0, stream>>>(convs_w, wfrag);
  k_pwt<<<256, 256, 0, stream>>>(pre_w, pwT);
  k_prefix<<<4, 256, 0, stream>>>(noise, pxA, pxB);

  (void)hipFuncSetAttribute((const void*)k_window,
                            hipFuncAttributeMaxDynamicSharedMemorySize, SMEM_BYTES);

  for (int s = 0; s < 4; ++s) {
    const float* pin = (s == 0) ? noise : (s == 1 ? pxA : (s == 2 ? pxB : pxA));
    float* pt = (s == 0) ? (pxA + 1024) : (s == 1 ? (pxB + 1024) : (s == 2 ? (pxA + 1024) : nullptr));
    k_window<<<NWIN, TPB, SMEM_BYTES, stream>>>(s, pin, pt, out, icgc, conv_b, conv0_w,
                                                wfrag, pwT, pre_b, mean_w, mean_b, std_w, std_b);
  }
}